// Round 7
// baseline (1509.801 us; speedup 1.0000x reference)
//
#include <hip/hip_runtime.h>
#include <hip/hip_bf16.h>

#define N_NODES 100000
#define N_EDGES 1600000
#define DIM 64

#define TILE 4096
#define B1 ((N_EDGES + TILE - 1) / TILE)        // 391 partition blocks
#define K1 ((N_NODES + 255) / 256)              // 391 buckets of 256 nodes
#define NCOUNTS (K1 * B1)                       // 152881
#define SCAN_BLOCK 1024
#define NSB ((NCOUNTS + SCAN_BLOCK - 1) / SCAN_BLOCK)  // 150
#define PACKB4 ((N_NODES * DIM / 4 + 255) / 256) // 6250 (exact: N*DIM = 6.4M)

typedef __attribute__((ext_vector_type(8))) short bf16x8;
typedef __attribute__((ext_vector_type(4))) float f32x4;

// ---------------- ws layout ----------------
// At      : 32 KB bf16 (combined epilogue matrix, transposed)
// cvec    : 1 KB
// records : E * 8 B  (u64 {hi=bf16x2 coef er,ei; lo=src | dst_local<<17});
//           written bucket-grouped by partition; NO node-sort (place deleted)
// hpack   : N*DIM*4B ({bf16 hr, bf16 hi} interleaved)
// counts  : NCOUNTS ints (hist -> in-place BLOCK-LOCAL exclusive prefix;
//           global offset = counts[ci] + bpre[ci>>10])
// bsum/bpre : NSB ints

__device__ __forceinline__ unsigned pack_bf16x2(float lo, float hi) {
  unsigned ulo = (unsigned)__hip_bfloat16_raw(__float2bfloat16(lo)).x;
  unsigned uhi = (unsigned)__hip_bfloat16_raw(__float2bfloat16(hi)).x;
  return ulo | (uhi << 16);
}
__device__ __forceinline__ float unpack_lo(unsigned u) {
  return __int_as_float((int)(u << 16));
}
__device__ __forceinline__ float unpack_hi(unsigned u) {
  return __int_as_float((int)(u & 0xFFFF0000u));
}
__device__ __forceinline__ unsigned short f2bf(float x) {
  return __hip_bfloat16_raw(__float2bfloat16(x)).x;
}

// Fused setup (r4-verified): pack_h (float4-vectorized), combined epilogue
// operator, per-(bucket,tile) LDS histogram (no global atomics, no memset).
__global__ __launch_bounds__(256) void setup_fused_kernel(
    const float* __restrict__ h_real, const float* __restrict__ h_imag,
    unsigned* __restrict__ hpack, const float* __restrict__ W1,
    const float* __restrict__ b1, const float* __restrict__ W2,
    const float* __restrict__ b2, unsigned short* __restrict__ At,
    float* __restrict__ cvec, const int* __restrict__ dst,
    int* __restrict__ counts) {
  const int bid = blockIdx.x;
  const int tid = threadIdx.x;
  if (bid < PACKB4) {
    const int i = bid * 256 + tid;  // covers N*DIM/4 exactly
    const float4 hr = ((const float4*)h_real)[i];
    const float4 hi = ((const float4*)h_imag)[i];
    uint4 o;
    o.x = pack_bf16x2(hr.x, hi.x);
    o.y = pack_bf16x2(hr.y, hi.y);
    o.z = pack_bf16x2(hr.z, hi.z);
    o.w = pack_bf16x2(hr.w, hi.w);
    ((uint4*)hpack)[i] = o;
    return;
  }
  if (bid < PACKB4 + 64) {
    const int idx = (bid - PACKB4) * 256 + tid;
    if (idx < 128 * 128) {
      const int n = idx >> 7, k = idx & 127;
      float v;
      if (n < 64) {
        v = (k < 64) ? W1[n * 64 + k] : -W2[n * 64 + (k - 64)];
      } else {
        const int nn = n - 64;
        if (k < 64) {
          float s = 0.0f;
          for (int j = 0; j < 64; ++j) s += W1[j * 64 + k] * W2[nn * 64 + j];
          v = s;
        } else {
          const int kk = k - 64;
          float s = 0.0f;
          for (int j = 0; j < 64; ++j) s += W2[j * 64 + kk] * W2[nn * 64 + j];
          v = W1[nn * 64 + kk] - s;
        }
      }
      At[n * 128 + k] = f2bf(v);
    }
    if (idx < 128) {
      if (idx < 64) {
        cvec[idx] = b1[idx] - b2[idx];
      } else {
        const int nn = idx - 64;
        float s = 0.0f;
        for (int j = 0; j < 64; ++j) s += (b1[j] - b2[j]) * W2[nn * 64 + j];
        cvec[idx] = s + b1[nn] + b2[nn];
      }
    }
    return;
  }
  // histogram role (LDS-local, per tile)
  __shared__ int lh[K1];
  const int hb = bid - PACKB4 - 64;
  for (int i = tid; i < K1; i += 256) lh[i] = 0;
  __syncthreads();
  const int e0 = hb * TILE;
  const int e1 = min(e0 + TILE, N_EDGES);
  for (int e = e0 + tid; e < e1; e += 256) atomicAdd(&lh[dst[e] >> 8], 1);
  __syncthreads();
  for (int b = tid; b < K1; b += 256) counts[b * B1 + hb] = lh[b];
}

// In-place: counts -> BLOCK-LOCAL exclusive prefix; bsum[blk] = block total.
__global__ __launch_bounds__(SCAN_BLOCK) void scan1_kernel(
    int* __restrict__ cnt, int* __restrict__ bsum) {
  __shared__ int wsum[16];
  const int tid = threadIdx.x;
  const int lane = tid & 63;
  const int w = tid >> 6;
  const int i = blockIdx.x * SCAN_BLOCK + tid;
  const int orig = (i < NCOUNTS) ? cnt[i] : 0;
  int v = orig;
#pragma unroll
  for (int off = 1; off < 64; off <<= 1) {
    int t = __shfl_up(v, off);
    if (lane >= off) v += t;
  }
  if (lane == 63) wsum[w] = v;
  __syncthreads();
  if (w == 0) {
    int s = (lane < 16) ? wsum[lane] : 0;
#pragma unroll
    for (int off = 1; off < 16; off <<= 1) {
      int t = __shfl_up(s, off);
      if (lane >= off) s += t;
    }
    if (lane < 16) wsum[lane] = s;
  }
  __syncthreads();
  const int wex = (w == 0) ? 0 : wsum[w - 1];
  if (i < NCOUNTS) cnt[i] = wex + v - orig;  // exclusive (block-local)
  if (tid == SCAN_BLOCK - 1) bsum[blockIdx.x] = wex + v;
}

// Scan of the NSB block sums -> exclusive bpre.
__global__ __launch_bounds__(256) void scan2_kernel(
    const int* __restrict__ bsum, int* __restrict__ bpre) {
  __shared__ int wsum[4];
  const int tid = threadIdx.x;
  const int lane = tid & 63;
  const int w = tid >> 6;
  const int orig = (tid < NSB) ? bsum[tid] : 0;
  int v = orig;
#pragma unroll
  for (int off = 1; off < 64; off <<= 1) {
    int t = __shfl_up(v, off);
    if (lane >= off) v += t;
  }
  if (lane == 63) wsum[w] = v;
  __syncthreads();
  if (w == 0) {
    int s = (lane < 4) ? wsum[lane] : 0;
#pragma unroll
    for (int off = 1; off < 4; off <<= 1) {
      int t = __shfl_up(s, off);
      if (lane >= off) s += t;
    }
    if (lane < 4) wsum[lane] = s;
  }
  __syncthreads();
  const int wex = (w == 0) ? 0 : wsum[w - 1];
  if (tid < NSB) bpre[tid] = wex + v - orig;  // exclusive
}

// Partition (r4-verified): stage tile in LDS sorted by bucket, write
// contiguous runs. Global offset = coffs[ci] + bpre[ci>>10].
__global__ __launch_bounds__(512) void partition_kernel(
    const int* __restrict__ src, const int* __restrict__ dst,
    const float* __restrict__ dvec,
    const float* __restrict__ w_real, const float* __restrict__ w_imag,
    const int* __restrict__ coffs, const int* __restrict__ bpre,
    unsigned long long* __restrict__ records) {
  __shared__ unsigned long long stage[TILE];  // 32 KB
  __shared__ unsigned short sb[TILE];         // 8 KB
  __shared__ int lhist[512];
  __shared__ int lbase[K1];
  __shared__ int lcur[K1];
  __shared__ int gbase[K1];
  __shared__ int wsum[8];
  const int tid = threadIdx.x;
  const int lane = tid & 63;
  const int w = tid >> 6;
  const int blk = blockIdx.x;
  const int e0 = blk * TILE;
  const int cnt_t = min(TILE, N_EDGES - e0);

  lhist[tid] = 0;
  __syncthreads();
  for (int j = tid; j < cnt_t; j += 512) atomicAdd(&lhist[dst[e0 + j] >> 8], 1);
  __syncthreads();
  const int myc = lhist[tid];
  int v = myc;
#pragma unroll
  for (int off = 1; off < 64; off <<= 1) {
    int t = __shfl_up(v, off);
    if (lane >= off) v += t;
  }
  if (lane == 63) wsum[w] = v;
  __syncthreads();
  if (w == 0) {
    int s = (lane < 8) ? wsum[lane] : 0;
#pragma unroll
    for (int off = 1; off < 8; off <<= 1) {
      int t = __shfl_up(s, off);
      if (lane >= off) s += t;
    }
    if (lane < 8) wsum[lane] = s;
  }
  __syncthreads();
  const int ex = v + ((w == 0) ? 0 : wsum[w - 1]) - myc;  // exclusive
  if (tid < K1) {
    lbase[tid] = ex;
    lcur[tid] = ex;
    const int ci = tid * B1 + blk;
    gbase[tid] = coffs[ci] + bpre[ci >> 10];
  }
  __syncthreads();

  for (int j = tid; j < cnt_t; j += 512) {
    const int e = e0 + j;
    const int t = dst[e];
    const int s = src[e];
    const int b = t >> 8;
    const float ds = dvec[s];
    const unsigned lo = (unsigned)s | ((unsigned)(t & 255) << 17);
    const unsigned hi = pack_bf16x2(ds * w_real[e], ds * w_imag[e]);
    const int r = atomicAdd(&lcur[b], 1);
    stage[r] = ((unsigned long long)hi << 32) | lo;
    sb[r] = (unsigned short)b;
  }
  __syncthreads();
  for (int i = tid; i < cnt_t; i += 512) {
    const int b = sb[i];
    records[gbase[b] + (i - lbase[b])] = stage[i];
  }
}

// Fused bucket pull. One block per HALF-bucket (128 nodes, full dims).
// Scans the whole 256-bucket record range (quarter-waves take equal chunks —
// balanced to ~1.6%), predicated on node-half ownership (quarter-uniform
// branch). Accumulates via LDS f32 atomics into zacc[128][128] (64 KiB,
// column rotated by +nloc to spread banks), then d-scale -> bf16 (overlaid
// in same LDS) -> MFMA epilogue. Replaces place+pull; no inc[], no caps.
// STATIC shared union (r7 de-risk: no dynamic-LDS launch dependency).
__global__ __launch_bounds__(512, 4) void pull_bucket_kernel(
    const uint2* __restrict__ records, const int* __restrict__ coffs,
    const int* __restrict__ bpre, const float* __restrict__ dvec,
    const unsigned* __restrict__ hpack, const unsigned short* __restrict__ At,
    const float* __restrict__ cvec, float* __restrict__ zr_out,
    float* __restrict__ zi_out) {
  __shared__ __align__(16) union {
    float zacc[128][128];            // 64 KiB f32 accumulator
    unsigned short zs[128][136];     // 34 KiB bf16 staged (overlay)
  } sm;
  float* zacc = &sm.zacc[0][0];
  const int tid = threadIdx.x;
  const int b256 = blockIdx.x >> 1;
  const int h = blockIdx.x & 1;           // node half of the bucket
  const int nbase = b256 * 256 + h * 128;
  const int gq = tid >> 4;                // quarter id 0..31
  const int m16 = tid & 15;               // dim group: dims 4*m16..+3
  const unsigned* __restrict__ hb = hpack + 4 * m16;

  // zero zacc
  {
    f32x4 z4 = (f32x4){0.f, 0.f, 0.f, 0.f};
    f32x4* za4 = (f32x4*)zacc;
#pragma unroll
    for (int i = 0; i < 8; ++i) za4[tid + i * 512] = z4;
  }
  __syncthreads();

  // bucket record range (global offsets via coffs + bpre)
  const int ci0 = b256 * B1;
  const int bstart = coffs[ci0] + bpre[ci0 >> 10];
  int bend;
  if (b256 == K1 - 1) {
    bend = N_EDGES;
  } else {
    const int ci1 = (b256 + 1) * B1;
    bend = coffs[ci1] + bpre[ci1 >> 10];
  }
  const int bcnt = bend - bstart;
  const int chunk = (bcnt + 31) >> 5;
  const int qs = bstart + gq * chunk;
  const int qe = min(qs + chunk, bend);

#define LOADQ(R, HV, OWN, NL)                                               \
  const int NL = ((R).x >> 17) & 255;                                       \
  const bool OWN = (NL >> 7) == h;                                          \
  uint4 HV = (uint4){0u, 0u, 0u, 0u};                                       \
  if (OWN)                                                                  \
    HV = *reinterpret_cast<const uint4*>(hb + (size_t)((R).x & 0x1FFFF) * DIM);

#define ACCQ(R, HV, OWN, NL)                                                \
  if (OWN) {                                                                \
    const int nloc = (NL) & 127;                                            \
    const float er = unpack_lo((R).y), ei = unpack_hi((R).y);               \
    float* zrow = zacc + nloc * 128;                                        \
    _Pragma("unroll") for (int d = 0; d < 4; ++d) {                         \
      const unsigned hu = ((const unsigned*)&HV)[d];                        \
      const float hr = unpack_lo(hu), hi_ = unpack_hi(hu);                  \
      const int col = (4 * m16 + d + nloc) & 63;                            \
      atomicAdd(zrow + col, er * hr - ei * hi_);                            \
      atomicAdd(zrow + 64 + col, ei * hr + er * hi_);                       \
    }                                                                       \
  }

  int p = qs;
  for (; p + 4 <= qe; p += 4) {
    const uint2 r0 = records[p];
    const uint2 r1 = records[p + 1];
    const uint2 r2 = records[p + 2];
    const uint2 r3 = records[p + 3];
    LOADQ(r0, hv0, o0, n0)
    LOADQ(r1, hv1, o1, n1)
    LOADQ(r2, hv2, o2, n2)
    LOADQ(r3, hv3, o3, n3)
    ACCQ(r0, hv0, o0, n0)
    ACCQ(r1, hv1, o1, n1)
    ACCQ(r2, hv2, o2, n2)
    ACCQ(r3, hv3, o3, n3)
  }
  for (; p < qe; ++p) {
    const uint2 r0 = records[p];
    LOADQ(r0, hv0, o0, n0)
    ACCQ(r0, hv0, o0, n0)
  }
#undef LOADQ
#undef ACCQ
  __syncthreads();

  // d-scale + bf16 pack, overlaid into sm.zs[128][136].
  // Read ALL f32 into regs, barrier, then write (overlay aliasing safe:
  // each row's 128 floats are read by exactly its 4 owning threads).
  {
    const int sn = tid >> 2;           // node 0..127
    const int j0 = (tid & 3) << 4;     // dim offset 0,16,32,48
    const int gnode = nbase + sn;
    const float dn = (gnode < N_NODES) ? dvec[gnode] : 0.f;
    float vr[16], vi[16];
    const float* zrow = zacc + sn * 128;
#pragma unroll
    for (int j = 0; j < 16; ++j) {
      const int col = (j0 + j + sn) & 63;  // undo rotation
      vr[j] = zrow[col] * dn;
      vi[j] = zrow[64 + col] * dn;
    }
    __syncthreads();
    unsigned* rowp = (unsigned*)(&sm.zs[sn][0]);
#pragma unroll
    for (int jj = 0; jj < 8; ++jj) {
      rowp[(j0 >> 1) + jj] = pack_bf16x2(vr[2 * jj], vr[2 * jj + 1]);
      rowp[32 + (j0 >> 1) + jj] = pack_bf16x2(vi[2 * jj], vi[2 * jj + 1]);
    }
  }
  __syncthreads();

  // MFMA epilogue: 8 node-groups x 8 feature-tiles = 64 tiles over 8 waves.
  {
    const unsigned short* zs = &sm.zs[0][0];
    const int wv = tid >> 6;
    const int lane = tid & 63;
    const int m = lane & 15;
    const int q = lane >> 4;
#pragma unroll
    for (int it = 0; it < 8; ++it) {
      const int tt = wv + it * 8;  // 0..63
      const int g = tt >> 3;       // node group
      const int ft = tt & 7;       // feature tile

      bf16x8 a[4];
#pragma unroll
      for (int c = 0; c < 4; ++c)
        a[c] = *reinterpret_cast<const bf16x8*>(
            zs + (size_t)(g * 16 + m) * 136 + c * 32 + q * 8);

      f32x4 acc = (f32x4){0.f, 0.f, 0.f, 0.f};
      const unsigned short* brow = At + (size_t)(ft * 16 + m) * 128 + q * 8;
#pragma unroll
      for (int c = 0; c < 4; ++c) {
        bf16x8 bfrag = *reinterpret_cast<const bf16x8*>(brow + c * 32);
        acc = __builtin_amdgcn_mfma_f32_16x16x32_bf16(a[c], bfrag, acc, 0, 0, 0);
      }

      const int nf = ft * 16 + m;
      const float bias = cvec[nf];
      float* outp = (nf < 64) ? zr_out : zi_out;
      const int nnn = nf & 63;
#pragma unroll
      for (int r = 0; r < 4; ++r) {
        const int node = nbase + g * 16 + q * 4 + r;
        if (node < N_NODES) outp[(size_t)node * 64 + nnn] = acc[r] + bias;
      }
    }
  }
}

extern "C" void kernel_launch(void* const* d_in, const int* in_sizes, int n_in,
                              void* d_out, int out_size, void* d_ws, size_t ws_size,
                              hipStream_t stream) {
  const float* h_real = (const float*)d_in[0];
  const float* h_imag = (const float*)d_in[1];
  const float* dvec   = (const float*)d_in[2];
  const float* w_real = (const float*)d_in[3];
  const float* w_imag = (const float*)d_in[4];
  const int*   src    = (const int*)d_in[5];
  const int*   dst    = (const int*)d_in[6];
  const float* W1     = (const float*)d_in[7];
  const float* b1     = (const float*)d_in[8];
  const float* W2     = (const float*)d_in[9];
  const float* b2     = (const float*)d_in[10];

  char* ws = (char*)d_ws;
  unsigned short* At = (unsigned short*)ws;                          // 32 KB
  float* cvec = (float*)(ws + 128 * 128 * 2);                        // 1 KB
  unsigned long long* records = (unsigned long long*)(ws + 33792);   // 12.8 MB
  unsigned* hpack = (unsigned*)(ws + 33792 + (size_t)N_EDGES * 8);   // 25.6 MB
  int* counts = (int*)(ws + 33792 + (size_t)N_EDGES * 8 + (size_t)N_NODES * DIM * 4);
  int* bsum = counts + NCOUNTS;
  int* bpre = bsum + NSB;

  float* zr_out = (float*)d_out;
  float* zi_out = zr_out + (size_t)N_NODES * DIM;

  setup_fused_kernel<<<PACKB4 + 64 + B1, 256, 0, stream>>>(
      h_real, h_imag, (unsigned*)hpack, W1, b1, W2, b2, At, cvec, dst, counts);
  scan1_kernel<<<NSB, SCAN_BLOCK, 0, stream>>>(counts, bsum);
  scan2_kernel<<<1, 256, 0, stream>>>(bsum, bpre);
  partition_kernel<<<B1, 512, 0, stream>>>(src, dst, dvec, w_real, w_imag,
                                           counts, bpre, records);
  pull_bucket_kernel<<<2 * K1, 512, 0, stream>>>(
      (const uint2*)records, counts, bpre, dvec, hpack, At, cvec,
      zr_out, zi_out);
}

// Round 8
// 271.688 us; speedup vs baseline: 5.5571x; 5.5571x over previous
//
#include <hip/hip_runtime.h>
#include <hip/hip_bf16.h>

#define N_NODES 100000
#define N_EDGES 1600000
#define DIM 64

#define TILE 4096
#define B1 ((N_EDGES + TILE - 1) / TILE)        // 391 partition blocks
#define K1 ((N_NODES + 255) / 256)              // 391 buckets of 256 nodes
#define NCOUNTS (K1 * B1)                       // 152881
#define SCAN_BLOCK 1024
#define NSB ((NCOUNTS + SCAN_BLOCK - 1) / SCAN_BLOCK)  // 150
#define PACKB4 ((N_NODES * DIM / 4 + 255) / 256) // 6250 (exact: N*DIM = 6.4M)
#define PLACE_CAP 4736                          // bucket mean 4096, sd 64 -> +10 sigma
#define NPW 8                                   // nodes per wave (pull)
#define PULLB (N_NODES / 32)                    // 3125 blocks, 32 nodes each

typedef __attribute__((ext_vector_type(8))) short bf16x8;
typedef __attribute__((ext_vector_type(4))) float f32x4;

#if defined(__has_builtin)
#if __has_builtin(__builtin_amdgcn_fdot2_f32_bf16)
#define HAVE_DOT2 1
typedef __attribute__((ext_vector_type(2))) __bf16 bf16x2v;
#endif
#endif

// ---------------- ws layout ----------------
// At      : 32 KB bf16 (combined epilogue matrix, transposed)
// cvec    : 1 KB
// records : E * 8 B  (u64 {hi=bf16x2 coef, lo=src | dst_local<<17}); written
//           bucket-grouped by partition, node-sorted IN PLACE by place
// hpack   : N*DIM*4B ({bf16 hr, bf16 hi} interleaved)
// counts  : NCOUNTS ints (hist -> in-place BLOCK-LOCAL exclusive prefix;
//           global offset = counts[ci] + bpre[ci>>10])
// bsum/bpre : NSB ints; inc : N ints (per-node inclusive prefix)

__device__ __forceinline__ unsigned pack_bf16x2(float lo, float hi) {
  unsigned ulo = (unsigned)__hip_bfloat16_raw(__float2bfloat16(lo)).x;
  unsigned uhi = (unsigned)__hip_bfloat16_raw(__float2bfloat16(hi)).x;
  return ulo | (uhi << 16);
}
__device__ __forceinline__ float unpack_lo(unsigned u) {
  return __int_as_float((int)(u << 16));
}
__device__ __forceinline__ float unpack_hi(unsigned u) {
  return __int_as_float((int)(u & 0xFFFF0000u));
}
__device__ __forceinline__ unsigned short f2bf(float x) {
  return __hip_bfloat16_raw(__float2bfloat16(x)).x;
}

// Fused setup (r4-verified): pack_h (float4-vectorized), combined epilogue
// operator, per-(bucket,tile) LDS histogram.
__global__ __launch_bounds__(256) void setup_fused_kernel(
    const float* __restrict__ h_real, const float* __restrict__ h_imag,
    unsigned* __restrict__ hpack, const float* __restrict__ W1,
    const float* __restrict__ b1, const float* __restrict__ W2,
    const float* __restrict__ b2, unsigned short* __restrict__ At,
    float* __restrict__ cvec, const int* __restrict__ dst,
    int* __restrict__ counts) {
  const int bid = blockIdx.x;
  const int tid = threadIdx.x;
  if (bid < PACKB4) {
    const int i = bid * 256 + tid;  // covers N*DIM/4 exactly
    const float4 hr = ((const float4*)h_real)[i];
    const float4 hi = ((const float4*)h_imag)[i];
    uint4 o;
    o.x = pack_bf16x2(hr.x, hi.x);
    o.y = pack_bf16x2(hr.y, hi.y);
    o.z = pack_bf16x2(hr.z, hi.z);
    o.w = pack_bf16x2(hr.w, hi.w);
    ((uint4*)hpack)[i] = o;
    return;
  }
  if (bid < PACKB4 + 64) {
    const int idx = (bid - PACKB4) * 256 + tid;
    if (idx < 128 * 128) {
      const int n = idx >> 7, k = idx & 127;
      float v;
      if (n < 64) {
        v = (k < 64) ? W1[n * 64 + k] : -W2[n * 64 + (k - 64)];
      } else {
        const int nn = n - 64;
        if (k < 64) {
          float s = 0.0f;
          for (int j = 0; j < 64; ++j) s += W1[j * 64 + k] * W2[nn * 64 + j];
          v = s;
        } else {
          const int kk = k - 64;
          float s = 0.0f;
          for (int j = 0; j < 64; ++j) s += W2[j * 64 + kk] * W2[nn * 64 + j];
          v = W1[nn * 64 + kk] - s;
        }
      }
      At[n * 128 + k] = f2bf(v);
    }
    if (idx < 128) {
      if (idx < 64) {
        cvec[idx] = b1[idx] - b2[idx];
      } else {
        const int nn = idx - 64;
        float s = 0.0f;
        for (int j = 0; j < 64; ++j) s += (b1[j] - b2[j]) * W2[nn * 64 + j];
        cvec[idx] = s + b1[nn] + b2[nn];
      }
    }
    return;
  }
  // histogram role (LDS-local, per tile)
  __shared__ int lh[K1];
  const int hb = bid - PACKB4 - 64;
  for (int i = tid; i < K1; i += 256) lh[i] = 0;
  __syncthreads();
  const int e0 = hb * TILE;
  const int e1 = min(e0 + TILE, N_EDGES);
  for (int e = e0 + tid; e < e1; e += 256) atomicAdd(&lh[dst[e] >> 8], 1);
  __syncthreads();
  for (int b = tid; b < K1; b += 256) counts[b * B1 + hb] = lh[b];
}

// In-place: counts -> BLOCK-LOCAL exclusive prefix; bsum[blk] = block total.
__global__ __launch_bounds__(SCAN_BLOCK) void scan1_kernel(
    int* __restrict__ cnt, int* __restrict__ bsum) {
  __shared__ int wsum[16];
  const int tid = threadIdx.x;
  const int lane = tid & 63;
  const int w = tid >> 6;
  const int i = blockIdx.x * SCAN_BLOCK + tid;
  const int orig = (i < NCOUNTS) ? cnt[i] : 0;
  int v = orig;
#pragma unroll
  for (int off = 1; off < 64; off <<= 1) {
    int t = __shfl_up(v, off);
    if (lane >= off) v += t;
  }
  if (lane == 63) wsum[w] = v;
  __syncthreads();
  if (w == 0) {
    int s = (lane < 16) ? wsum[lane] : 0;
#pragma unroll
    for (int off = 1; off < 16; off <<= 1) {
      int t = __shfl_up(s, off);
      if (lane >= off) s += t;
    }
    if (lane < 16) wsum[lane] = s;
  }
  __syncthreads();
  const int wex = (w == 0) ? 0 : wsum[w - 1];
  if (i < NCOUNTS) cnt[i] = wex + v - orig;  // exclusive (block-local)
  if (tid == SCAN_BLOCK - 1) bsum[blockIdx.x] = wex + v;
}

// Scan of the NSB block sums -> exclusive bpre.
__global__ __launch_bounds__(256) void scan2_kernel(
    const int* __restrict__ bsum, int* __restrict__ bpre) {
  __shared__ int wsum[4];
  const int tid = threadIdx.x;
  const int lane = tid & 63;
  const int w = tid >> 6;
  const int orig = (tid < NSB) ? bsum[tid] : 0;
  int v = orig;
#pragma unroll
  for (int off = 1; off < 64; off <<= 1) {
    int t = __shfl_up(v, off);
    if (lane >= off) v += t;
  }
  if (lane == 63) wsum[w] = v;
  __syncthreads();
  if (w == 0) {
    int s = (lane < 4) ? wsum[lane] : 0;
#pragma unroll
    for (int off = 1; off < 4; off <<= 1) {
      int t = __shfl_up(s, off);
      if (lane >= off) s += t;
    }
    if (lane < 4) wsum[lane] = s;
  }
  __syncthreads();
  const int wex = (w == 0) ? 0 : wsum[w - 1];
  if (tid < NSB) bpre[tid] = wex + v - orig;  // exclusive
}

// Partition (r4-verified): stage tile in LDS sorted by bucket, write
// contiguous runs. Global offset = coffs[ci] + bpre[ci>>10].
__global__ __launch_bounds__(512) void partition_kernel(
    const int* __restrict__ src, const int* __restrict__ dst,
    const float* __restrict__ dvec,
    const float* __restrict__ w_real, const float* __restrict__ w_imag,
    const int* __restrict__ coffs, const int* __restrict__ bpre,
    unsigned long long* __restrict__ records) {
  __shared__ unsigned long long stage[TILE];  // 32 KB
  __shared__ unsigned short sb[TILE];         // 8 KB
  __shared__ int lhist[512];
  __shared__ int lbase[K1];
  __shared__ int lcur[K1];
  __shared__ int gbase[K1];
  __shared__ int wsum[8];
  const int tid = threadIdx.x;
  const int lane = tid & 63;
  const int w = tid >> 6;
  const int blk = blockIdx.x;
  const int e0 = blk * TILE;
  const int cnt_t = min(TILE, N_EDGES - e0);

  lhist[tid] = 0;
  __syncthreads();
  for (int j = tid; j < cnt_t; j += 512) atomicAdd(&lhist[dst[e0 + j] >> 8], 1);
  __syncthreads();
  const int myc = lhist[tid];
  int v = myc;
#pragma unroll
  for (int off = 1; off < 64; off <<= 1) {
    int t = __shfl_up(v, off);
    if (lane >= off) v += t;
  }
  if (lane == 63) wsum[w] = v;
  __syncthreads();
  if (w == 0) {
    int s = (lane < 8) ? wsum[lane] : 0;
#pragma unroll
    for (int off = 1; off < 8; off <<= 1) {
      int t = __shfl_up(s, off);
      if (lane >= off) s += t;
    }
    if (lane < 8) wsum[lane] = s;
  }
  __syncthreads();
  const int ex = v + ((w == 0) ? 0 : wsum[w - 1]) - myc;  // exclusive
  if (tid < K1) {
    lbase[tid] = ex;
    lcur[tid] = ex;
    const int ci = tid * B1 + blk;
    gbase[tid] = coffs[ci] + bpre[ci >> 10];
  }
  __syncthreads();

  for (int j = tid; j < cnt_t; j += 512) {
    const int e = e0 + j;
    const int t = dst[e];
    const int s = src[e];
    const int b = t >> 8;
    const float ds = dvec[s];
    const unsigned lo = (unsigned)s | ((unsigned)(t & 255) << 17);
    const unsigned hi = pack_bf16x2(ds * w_real[e], ds * w_imag[e]);
    const int r = atomicAdd(&lcur[b], 1);
    stage[r] = ((unsigned long long)hi << 32) | lo;
    sb[r] = (unsigned short)b;
  }
  __syncthreads();
  for (int i = tid; i < cnt_t; i += 512) {
    const int b = sb[i];
    records[gbase[b] + (i - lbase[b])] = stage[i];
  }
}

// Place (r4-verified): one block per 256-node bucket; stage region in LDS,
// per-node count + wave-shuffle scan, re-scatter IN PLACE to node order.
// Writes the global per-node inclusive prefix (inc).
__global__ __launch_bounds__(256) void place_kernel(
    unsigned long long* __restrict__ records, const int* __restrict__ coffs,
    const int* __restrict__ bpre, int* __restrict__ inc) {
  const int b = blockIdx.x;
  const int tid = threadIdx.x;
  const int lane = tid & 63;
  const int w = tid >> 6;
  const int ci0 = b * B1;
  const int bstart = coffs[ci0] + bpre[ci0 >> 10];
  int bend;
  if (b == K1 - 1) {
    bend = N_EDGES;
  } else {
    const int ci1 = (b + 1) * B1;
    bend = coffs[ci1] + bpre[ci1 >> 10];
  }
  const int cnt = min(bend - bstart, PLACE_CAP);
  const int nbase = b << 8;
  const int nn = min(256, N_NODES - nbase);

  __shared__ unsigned long long stage[PLACE_CAP];  // 37 KB
  __shared__ int ncnt[256];
  __shared__ int ncur[256];
  __shared__ int wsum[4];

  ncnt[tid] = 0;
  __syncthreads();
  for (int i = tid; i < cnt; i += 256) {
    const unsigned long long rec = records[bstart + i];
    stage[i] = rec;
    atomicAdd(&ncnt[((unsigned)rec >> 17) & 255], 1);
  }
  __syncthreads();
  const int myc = ncnt[tid];
  int v = myc;
#pragma unroll
  for (int off = 1; off < 64; off <<= 1) {
    int t = __shfl_up(v, off);
    if (lane >= off) v += t;
  }
  if (lane == 63) wsum[w] = v;
  __syncthreads();
  if (w == 0) {
    int s = (lane < 4) ? wsum[lane] : 0;
#pragma unroll
    for (int off = 1; off < 4; off <<= 1) {
      int t = __shfl_up(s, off);
      if (lane >= off) s += t;
    }
    if (lane < 4) wsum[lane] = s;
  }
  __syncthreads();
  const int incl = v + ((w == 0) ? 0 : wsum[w - 1]);
  const int base = bstart + incl - myc;
  ncur[tid] = base;
  if (tid < nn) inc[nbase + tid] = base + myc;
  __syncthreads();
  for (int i = tid; i < cnt; i += 256) {
    const unsigned long long rec = stage[i];
    const int pos = atomicAdd(&ncur[((unsigned)rec >> 17) & 255], 1);
    records[pos] = rec;
  }
}

// Pull (r5-verified structure): branch-free quarter-split dot loop,
// 4 waves x 8 nodes = 32 nodes per 256-thread block. Max occupancy
// (launch_bounds 256,8; 8.7 KB LDS). Only delta vs r5: records carry
// dst_local in bits 17+, so hpack index masks with 0x1FFFF.
__global__ __launch_bounds__(256, 8) void pull_fused_kernel(
    const uint2* __restrict__ records, const int* __restrict__ inc,
    const float* __restrict__ dvec, const unsigned* __restrict__ hpack,
    const unsigned short* __restrict__ At, const float* __restrict__ cvec,
    float* __restrict__ zr_out, float* __restrict__ zi_out) {
  __shared__ __align__(16) unsigned short zs[32][136];  // 8.7 KB
  const int tid = threadIdx.x;
  const int lane = tid & 63;
  const int wave = tid >> 6;   // 0..3
  const int q4 = lane >> 4;    // quarter id (edge interleave)
  const int m16 = lane & 15;   // dim group: dims 4*m16 .. 4*m16+3
  const int node0 = blockIdx.x * 32;  // grid = N/32 exact
  const unsigned* __restrict__ hb = hpack + 4 * m16;

#if HAVE_DOT2
#define DOT2(acc, w_, h_)                                                   \
  acc = __builtin_amdgcn_fdot2_f32_bf16(__builtin_bit_cast(bf16x2v, (w_)),  \
                                        __builtin_bit_cast(bf16x2v, (h_)),  \
                                        acc, false)
#else
#define DOT2(acc, w_, h_)                                                   \
  {                                                                         \
    const float _wl = unpack_lo(w_), _wh = unpack_hi(w_);                   \
    const float _hl = unpack_lo(h_), _hh = unpack_hi(h_);                   \
    acc += _wl * _hl + _wh * _hh;                                           \
  }
#endif

#define ACC4(RR)                                                            \
  {                                                                         \
    const unsigned wneg = (RR).y ^ 0x80000000u;                             \
    const unsigned wswp = ((RR).y >> 16) | ((RR).y << 16);                  \
    const uint4 hv = *reinterpret_cast<const uint4*>(                       \
        hb + (size_t)((RR).x & 0x1FFFF) * DIM);                             \
    DOT2(sr0, wneg, hv.x); DOT2(si0, wswp, hv.x);                           \
    DOT2(sr1, wneg, hv.y); DOT2(si1, wswp, hv.y);                           \
    DOT2(sr2, wneg, hv.z); DOT2(si2, wswp, hv.z);                           \
    DOT2(sr3, wneg, hv.w); DOT2(si3, wswp, hv.w);                           \
  }

  for (int j = 0; j < NPW; ++j) {
    const int n = node0 + wave * NPW + j;
    const int start = (n == 0) ? 0 : inc[n - 1];
    const int end = inc[n];
    const int deg = end - start;

    float sr0 = 0.f, sr1 = 0.f, sr2 = 0.f, sr3 = 0.f;
    float si0 = 0.f, si1 = 0.f, si2 = 0.f, si3 = 0.f;

    int p = start + q4;
    const int nfull = deg >> 2;
    int i = 0;
    for (; i + 2 <= nfull; i += 2) {
      const uint2 r0 = records[p];
      const uint2 r1 = records[p + 4];
      ACC4(r0);
      ACC4(r1);
      p += 8;
    }
    if (i < nfull) {
      const uint2 r0 = records[p];
      ACC4(r0);
      p += 4;
    }
    if (p < end) {
      const uint2 r0 = records[p];
      ACC4(r0);
    }

    // Merge the 4 quarter-partials (lanes L, L^16, L^32, L^48 share dims).
#define QRED(v)                  \
    v += __shfl_xor(v, 16);      \
    v += __shfl_xor(v, 32);
    QRED(sr0) QRED(sr1) QRED(sr2) QRED(sr3)
    QRED(si0) QRED(si1) QRED(si2) QRED(si3)
#undef QRED

    const float dn = dvec[n];
    if (lane < 16) {
      const int zl = wave * NPW + j;
      uint2 rv, iv;
      rv.x = pack_bf16x2(dn * sr0, dn * sr1);
      rv.y = pack_bf16x2(dn * sr2, dn * sr3);
      iv.x = pack_bf16x2(dn * si0, dn * si1);
      iv.y = pack_bf16x2(dn * si2, dn * si3);
      *reinterpret_cast<uint2*>(&zs[zl][4 * lane]) = rv;
      *reinterpret_cast<uint2*>(&zs[zl][64 + 4 * lane]) = iv;
    }
  }
#undef ACC4
#undef DOT2
  __syncthreads();

  // Epilogue: Out[node][f] = sum_k Zcat[node][k]*A_comb[k][f] + cvec[f].
  // 16 tiles (2 node-halves x 8 feature-tiles); wave t does tiles t, t+4, ...
  {
    const int m = lane & 15;
    const int q = lane >> 4;
#pragma unroll
    for (int kk = 0; kk < 4; ++kk) {
      const int tt = wave + kk * 4;  // 0..15
      const int nh = tt >> 3;        // node half
      const int ft = tt & 7;         // feature tile

      bf16x8 a[4];
#pragma unroll
      for (int c = 0; c < 4; ++c)
        a[c] = *reinterpret_cast<const bf16x8*>(&zs[nh * 16 + m][c * 32 + q * 8]);

      f32x4 acc = (f32x4){0.f, 0.f, 0.f, 0.f};
      const unsigned short* brow = At + (size_t)(ft * 16 + m) * 128 + q * 8;
#pragma unroll
      for (int c = 0; c < 4; ++c) {
        bf16x8 bfrag = *reinterpret_cast<const bf16x8*>(brow + c * 32);
        acc = __builtin_amdgcn_mfma_f32_16x16x32_bf16(a[c], bfrag, acc, 0, 0, 0);
      }

      const int nf = ft * 16 + m;
      const float bias = cvec[nf];
      float* outp = (nf < 64) ? zr_out : zi_out;
      const int nnn = nf & 63;
#pragma unroll
      for (int r = 0; r < 4; ++r) {
        const int node = node0 + nh * 16 + q * 4 + r;
        outp[(size_t)node * 64 + nnn] = acc[r] + bias;
      }
    }
  }
}

extern "C" void kernel_launch(void* const* d_in, const int* in_sizes, int n_in,
                              void* d_out, int out_size, void* d_ws, size_t ws_size,
                              hipStream_t stream) {
  const float* h_real = (const float*)d_in[0];
  const float* h_imag = (const float*)d_in[1];
  const float* dvec   = (const float*)d_in[2];
  const float* w_real = (const float*)d_in[3];
  const float* w_imag = (const float*)d_in[4];
  const int*   src    = (const int*)d_in[5];
  const int*   dst    = (const int*)d_in[6];
  const float* W1     = (const float*)d_in[7];
  const float* b1     = (const float*)d_in[8];
  const float* W2     = (const float*)d_in[9];
  const float* b2     = (const float*)d_in[10];

  char* ws = (char*)d_ws;
  unsigned short* At = (unsigned short*)ws;                          // 32 KB
  float* cvec = (float*)(ws + 128 * 128 * 2);                        // 1 KB
  unsigned long long* records = (unsigned long long*)(ws + 33792);   // 12.8 MB
  unsigned* hpack = (unsigned*)(ws + 33792 + (size_t)N_EDGES * 8);   // 25.6 MB
  int* counts = (int*)(ws + 33792 + (size_t)N_EDGES * 8 + (size_t)N_NODES * DIM * 4);
  int* bsum = counts + NCOUNTS;
  int* bpre = bsum + NSB;
  int* inc  = bpre + NSB;

  float* zr_out = (float*)d_out;
  float* zi_out = zr_out + (size_t)N_NODES * DIM;

  setup_fused_kernel<<<PACKB4 + 64 + B1, 256, 0, stream>>>(
      h_real, h_imag, (unsigned*)hpack, W1, b1, W2, b2, At, cvec, dst, counts);
  scan1_kernel<<<NSB, SCAN_BLOCK, 0, stream>>>(counts, bsum);
  scan2_kernel<<<1, 256, 0, stream>>>(bsum, bpre);
  partition_kernel<<<B1, 512, 0, stream>>>(src, dst, dvec, w_real, w_imag,
                                           counts, bpre, records);
  place_kernel<<<K1, 256, 0, stream>>>(records, counts, bpre, inc);
  pull_fused_kernel<<<PULLB, 256, 0, stream>>>(
      (const uint2*)records, inc, dvec, hpack, At, cvec, zr_out, zi_out);
}

// Round 9
// 265.093 us; speedup vs baseline: 5.6954x; 1.0249x over previous
//
#include <hip/hip_runtime.h>
#include <hip/hip_bf16.h>

#define N_NODES 100000
#define N_EDGES 1600000
#define DIM 64

#define TILE 4096
#define B1 ((N_EDGES + TILE - 1) / TILE)        // 391 partition blocks
#define K1 ((N_NODES + 255) / 256)              // 391 buckets of 256 nodes
#define NCOUNTS (K1 * B1)                       // 152881
#define SCAN_BLOCK 1024
#define NSB ((NCOUNTS + SCAN_BLOCK - 1) / SCAN_BLOCK)  // 150
#define PACKB4 ((N_NODES * DIM / 4 + 255) / 256) // 6250 (exact: N*DIM = 6.4M)
#define PLACE_CAP 4736                          // bucket mean 4096, sd 64 -> +10 sigma
#define PULLB (N_NODES / 16)                    // 6250 blocks, 16 nodes each

typedef __attribute__((ext_vector_type(8))) short bf16x8;
typedef __attribute__((ext_vector_type(4))) float f32x4;

#if defined(__has_builtin)
#if __has_builtin(__builtin_amdgcn_fdot2_f32_bf16)
#define HAVE_DOT2 1
typedef __attribute__((ext_vector_type(2))) __bf16 bf16x2v;
#endif
#endif

// ---------------- ws layout ----------------
// At      : 32 KB bf16 (combined epilogue matrix, transposed)
// cvec    : 1 KB
// records : E * 8 B  (u64 {hi=bf16x2 coef, lo=src | dst_local<<17}); written
//           bucket-grouped by partition, node-sorted IN PLACE by place
// hpack   : N*DIM*4B ({bf16 hr, bf16 hi} interleaved)
// counts  : NCOUNTS ints (hist -> in-place BLOCK-LOCAL exclusive prefix;
//           global offset = counts[ci] + bpre[ci>>10])
// bsum/bpre : NSB ints; inc : N ints (per-node inclusive prefix)

__device__ __forceinline__ unsigned pack_bf16x2(float lo, float hi) {
  unsigned ulo = (unsigned)__hip_bfloat16_raw(__float2bfloat16(lo)).x;
  unsigned uhi = (unsigned)__hip_bfloat16_raw(__float2bfloat16(hi)).x;
  return ulo | (uhi << 16);
}
__device__ __forceinline__ float unpack_lo(unsigned u) {
  return __int_as_float((int)(u << 16));
}
__device__ __forceinline__ float unpack_hi(unsigned u) {
  return __int_as_float((int)(u & 0xFFFF0000u));
}
__device__ __forceinline__ unsigned short f2bf(float x) {
  return __hip_bfloat16_raw(__float2bfloat16(x)).x;
}

// Fused setup (r8-verified): pack_h (float4-vectorized), combined epilogue
// operator, per-(bucket,tile) LDS histogram.
__global__ __launch_bounds__(256) void setup_fused_kernel(
    const float* __restrict__ h_real, const float* __restrict__ h_imag,
    unsigned* __restrict__ hpack, const float* __restrict__ W1,
    const float* __restrict__ b1, const float* __restrict__ W2,
    const float* __restrict__ b2, unsigned short* __restrict__ At,
    float* __restrict__ cvec, const int* __restrict__ dst,
    int* __restrict__ counts) {
  const int bid = blockIdx.x;
  const int tid = threadIdx.x;
  if (bid < PACKB4) {
    const int i = bid * 256 + tid;  // covers N*DIM/4 exactly
    const float4 hr = ((const float4*)h_real)[i];
    const float4 hi = ((const float4*)h_imag)[i];
    uint4 o;
    o.x = pack_bf16x2(hr.x, hi.x);
    o.y = pack_bf16x2(hr.y, hi.y);
    o.z = pack_bf16x2(hr.z, hi.z);
    o.w = pack_bf16x2(hr.w, hi.w);
    ((uint4*)hpack)[i] = o;
    return;
  }
  if (bid < PACKB4 + 64) {
    const int idx = (bid - PACKB4) * 256 + tid;
    if (idx < 128 * 128) {
      const int n = idx >> 7, k = idx & 127;
      float v;
      if (n < 64) {
        v = (k < 64) ? W1[n * 64 + k] : -W2[n * 64 + (k - 64)];
      } else {
        const int nn = n - 64;
        if (k < 64) {
          float s = 0.0f;
          for (int j = 0; j < 64; ++j) s += W1[j * 64 + k] * W2[nn * 64 + j];
          v = s;
        } else {
          const int kk = k - 64;
          float s = 0.0f;
          for (int j = 0; j < 64; ++j) s += W2[j * 64 + kk] * W2[nn * 64 + j];
          v = W1[nn * 64 + kk] - s;
        }
      }
      At[n * 128 + k] = f2bf(v);
    }
    if (idx < 128) {
      if (idx < 64) {
        cvec[idx] = b1[idx] - b2[idx];
      } else {
        const int nn = idx - 64;
        float s = 0.0f;
        for (int j = 0; j < 64; ++j) s += (b1[j] - b2[j]) * W2[nn * 64 + j];
        cvec[idx] = s + b1[nn] + b2[nn];
      }
    }
    return;
  }
  // histogram role (LDS-local, per tile)
  __shared__ int lh[K1];
  const int hb = bid - PACKB4 - 64;
  for (int i = tid; i < K1; i += 256) lh[i] = 0;
  __syncthreads();
  const int e0 = hb * TILE;
  const int e1 = min(e0 + TILE, N_EDGES);
  for (int e = e0 + tid; e < e1; e += 256) atomicAdd(&lh[dst[e] >> 8], 1);
  __syncthreads();
  for (int b = tid; b < K1; b += 256) counts[b * B1 + hb] = lh[b];
}

// In-place: counts -> BLOCK-LOCAL exclusive prefix; bsum[blk] = block total.
__global__ __launch_bounds__(SCAN_BLOCK) void scan1_kernel(
    int* __restrict__ cnt, int* __restrict__ bsum) {
  __shared__ int wsum[16];
  const int tid = threadIdx.x;
  const int lane = tid & 63;
  const int w = tid >> 6;
  const int i = blockIdx.x * SCAN_BLOCK + tid;
  const int orig = (i < NCOUNTS) ? cnt[i] : 0;
  int v = orig;
#pragma unroll
  for (int off = 1; off < 64; off <<= 1) {
    int t = __shfl_up(v, off);
    if (lane >= off) v += t;
  }
  if (lane == 63) wsum[w] = v;
  __syncthreads();
  if (w == 0) {
    int s = (lane < 16) ? wsum[lane] : 0;
#pragma unroll
    for (int off = 1; off < 16; off <<= 1) {
      int t = __shfl_up(s, off);
      if (lane >= off) s += t;
    }
    if (lane < 16) wsum[lane] = s;
  }
  __syncthreads();
  const int wex = (w == 0) ? 0 : wsum[w - 1];
  if (i < NCOUNTS) cnt[i] = wex + v - orig;  // exclusive (block-local)
  if (tid == SCAN_BLOCK - 1) bsum[blockIdx.x] = wex + v;
}

// Scan of the NSB block sums -> exclusive bpre.
__global__ __launch_bounds__(256) void scan2_kernel(
    const int* __restrict__ bsum, int* __restrict__ bpre) {
  __shared__ int wsum[4];
  const int tid = threadIdx.x;
  const int lane = tid & 63;
  const int w = tid >> 6;
  const int orig = (tid < NSB) ? bsum[tid] : 0;
  int v = orig;
#pragma unroll
  for (int off = 1; off < 64; off <<= 1) {
    int t = __shfl_up(v, off);
    if (lane >= off) v += t;
  }
  if (lane == 63) wsum[w] = v;
  __syncthreads();
  if (w == 0) {
    int s = (lane < 4) ? wsum[lane] : 0;
#pragma unroll
    for (int off = 1; off < 4; off <<= 1) {
      int t = __shfl_up(s, off);
      if (lane >= off) s += t;
    }
    if (lane < 4) wsum[lane] = s;
  }
  __syncthreads();
  const int wex = (w == 0) ? 0 : wsum[w - 1];
  if (tid < NSB) bpre[tid] = wex + v - orig;  // exclusive
}

// Partition (r8-verified): stage tile in LDS sorted by bucket, write
// contiguous runs. Global offset = coffs[ci] + bpre[ci>>10].
__global__ __launch_bounds__(512) void partition_kernel(
    const int* __restrict__ src, const int* __restrict__ dst,
    const float* __restrict__ dvec,
    const float* __restrict__ w_real, const float* __restrict__ w_imag,
    const int* __restrict__ coffs, const int* __restrict__ bpre,
    unsigned long long* __restrict__ records) {
  __shared__ unsigned long long stage[TILE];  // 32 KB
  __shared__ unsigned short sb[TILE];         // 8 KB
  __shared__ int lhist[512];
  __shared__ int lbase[K1];
  __shared__ int lcur[K1];
  __shared__ int gbase[K1];
  __shared__ int wsum[8];
  const int tid = threadIdx.x;
  const int lane = tid & 63;
  const int w = tid >> 6;
  const int blk = blockIdx.x;
  const int e0 = blk * TILE;
  const int cnt_t = min(TILE, N_EDGES - e0);

  lhist[tid] = 0;
  __syncthreads();
  for (int j = tid; j < cnt_t; j += 512) atomicAdd(&lhist[dst[e0 + j] >> 8], 1);
  __syncthreads();
  const int myc = lhist[tid];
  int v = myc;
#pragma unroll
  for (int off = 1; off < 64; off <<= 1) {
    int t = __shfl_up(v, off);
    if (lane >= off) v += t;
  }
  if (lane == 63) wsum[w] = v;
  __syncthreads();
  if (w == 0) {
    int s = (lane < 8) ? wsum[lane] : 0;
#pragma unroll
    for (int off = 1; off < 8; off <<= 1) {
      int t = __shfl_up(s, off);
      if (lane >= off) s += t;
    }
    if (lane < 8) wsum[lane] = s;
  }
  __syncthreads();
  const int ex = v + ((w == 0) ? 0 : wsum[w - 1]) - myc;  // exclusive
  if (tid < K1) {
    lbase[tid] = ex;
    lcur[tid] = ex;
    const int ci = tid * B1 + blk;
    gbase[tid] = coffs[ci] + bpre[ci >> 10];
  }
  __syncthreads();

  for (int j = tid; j < cnt_t; j += 512) {
    const int e = e0 + j;
    const int t = dst[e];
    const int s = src[e];
    const int b = t >> 8;
    const float ds = dvec[s];
    const unsigned lo = (unsigned)s | ((unsigned)(t & 255) << 17);
    const unsigned hi = pack_bf16x2(ds * w_real[e], ds * w_imag[e]);
    const int r = atomicAdd(&lcur[b], 1);
    stage[r] = ((unsigned long long)hi << 32) | lo;
    sb[r] = (unsigned short)b;
  }
  __syncthreads();
  for (int i = tid; i < cnt_t; i += 512) {
    const int b = sb[i];
    records[gbase[b] + (i - lbase[b])] = stage[i];
  }
}

// Place (r8-verified): one block per 256-node bucket; stage region in LDS,
// per-node count + wave-shuffle scan, re-scatter IN PLACE to node order.
// Writes the global per-node inclusive prefix (inc).
__global__ __launch_bounds__(256) void place_kernel(
    unsigned long long* __restrict__ records, const int* __restrict__ coffs,
    const int* __restrict__ bpre, int* __restrict__ inc) {
  const int b = blockIdx.x;
  const int tid = threadIdx.x;
  const int lane = tid & 63;
  const int w = tid >> 6;
  const int ci0 = b * B1;
  const int bstart = coffs[ci0] + bpre[ci0 >> 10];
  int bend;
  if (b == K1 - 1) {
    bend = N_EDGES;
  } else {
    const int ci1 = (b + 1) * B1;
    bend = coffs[ci1] + bpre[ci1 >> 10];
  }
  const int cnt = min(bend - bstart, PLACE_CAP);
  const int nbase = b << 8;
  const int nn = min(256, N_NODES - nbase);

  __shared__ unsigned long long stage[PLACE_CAP];  // 37 KB
  __shared__ int ncnt[256];
  __shared__ int ncur[256];
  __shared__ int wsum[4];

  ncnt[tid] = 0;
  __syncthreads();
  for (int i = tid; i < cnt; i += 256) {
    const unsigned long long rec = records[bstart + i];
    stage[i] = rec;
    atomicAdd(&ncnt[((unsigned)rec >> 17) & 255], 1);
  }
  __syncthreads();
  const int myc = ncnt[tid];
  int v = myc;
#pragma unroll
  for (int off = 1; off < 64; off <<= 1) {
    int t = __shfl_up(v, off);
    if (lane >= off) v += t;
  }
  if (lane == 63) wsum[w] = v;
  __syncthreads();
  if (w == 0) {
    int s = (lane < 4) ? wsum[lane] : 0;
#pragma unroll
    for (int off = 1; off < 4; off <<= 1) {
      int t = __shfl_up(s, off);
      if (lane >= off) s += t;
    }
    if (lane < 4) wsum[lane] = s;
  }
  __syncthreads();
  const int incl = v + ((w == 0) ? 0 : wsum[w - 1]);
  const int base = bstart + incl - myc;
  ncur[tid] = base;
  if (tid < nn) inc[nbase + tid] = base + myc;
  __syncthreads();
  for (int i = tid; i < cnt; i += 256) {
    const unsigned long long rec = stage[i];
    const int pos = atomicAdd(&ncur[((unsigned)rec >> 17) & 255], 1);
    records[pos] = rec;
  }
}

// Pull v5: 8 waves x 2 nodes = 16 nodes per 512-thread block (50k waves ->
// high TLP), quarter-split dot loop with UNROLL-4 explicit load staging
// (4 records + 4 independent 256B row gathers in flight). Epilogue stages
// through LDS and writes full 256B rows as float4 (coalesced).
__global__ __launch_bounds__(512, 8) void pull_fused_kernel(
    const uint2* __restrict__ records, const int* __restrict__ inc,
    const float* __restrict__ dvec, const unsigned* __restrict__ hpack,
    const unsigned short* __restrict__ At, const float* __restrict__ cvec,
    float* __restrict__ zr_out, float* __restrict__ zi_out) {
  __shared__ __align__(16) unsigned short zs[16][136];  // 4.25 KB
  __shared__ __align__(16) float outbuf[16][132];       // 8.25 KB (pad 132)
  const int tid = threadIdx.x;
  const int lane = tid & 63;
  const int wave = tid >> 6;   // 0..7
  const int q4 = lane >> 4;    // quarter id (edge interleave)
  const int m16 = lane & 15;   // dim group: dims 4*m16 .. 4*m16+3
  const int node0 = blockIdx.x * 16;  // grid = N/16 exact
  const unsigned* __restrict__ hb = hpack + 4 * m16;

#if HAVE_DOT2
#define DOT2(acc, w_, h_)                                                   \
  acc = __builtin_amdgcn_fdot2_f32_bf16(__builtin_bit_cast(bf16x2v, (w_)),  \
                                        __builtin_bit_cast(bf16x2v, (h_)),  \
                                        acc, false)
#else
#define DOT2(acc, w_, h_)                                                   \
  {                                                                         \
    const float _wl = unpack_lo(w_), _wh = unpack_hi(w_);                   \
    const float _hl = unpack_lo(h_), _hh = unpack_hi(h_);                   \
    acc += _wl * _hl + _wh * _hh;                                           \
  }
#endif

#define GATH(RR) \
  (*reinterpret_cast<const uint4*>(hb + (size_t)((RR).x & 0x1FFFF) * DIM))

#define DOTS(RR, HV)                                                        \
  {                                                                         \
    const unsigned wneg = (RR).y ^ 0x80000000u;                             \
    const unsigned wswp = ((RR).y >> 16) | ((RR).y << 16);                  \
    DOT2(sr0, wneg, (HV).x); DOT2(si0, wswp, (HV).x);                       \
    DOT2(sr1, wneg, (HV).y); DOT2(si1, wswp, (HV).y);                       \
    DOT2(sr2, wneg, (HV).z); DOT2(si2, wswp, (HV).z);                       \
    DOT2(sr3, wneg, (HV).w); DOT2(si3, wswp, (HV).w);                       \
  }

  for (int j = 0; j < 2; ++j) {
    const int n = node0 + wave * 2 + j;
    const int start = (n == 0) ? 0 : inc[n - 1];
    const int end = inc[n];
    const int deg = end - start;

    float sr0 = 0.f, sr1 = 0.f, sr2 = 0.f, sr3 = 0.f;
    float si0 = 0.f, si1 = 0.f, si2 = 0.f, si3 = 0.f;

    int p = start + q4;
    const int nfull = deg >> 2;
    int i = 0;
    for (; i + 4 <= nfull; i += 4) {
      const uint2 ra = records[p];
      const uint2 rb = records[p + 4];
      const uint2 rc = records[p + 8];
      const uint2 rd = records[p + 12];
      const uint4 ha = GATH(ra);
      const uint4 hbv = GATH(rb);
      const uint4 hc = GATH(rc);
      const uint4 hd = GATH(rd);
      DOTS(ra, ha) DOTS(rb, hbv) DOTS(rc, hc) DOTS(rd, hd)
      p += 16;
    }
    for (; i + 2 <= nfull; i += 2) {
      const uint2 ra = records[p];
      const uint2 rb = records[p + 4];
      const uint4 ha = GATH(ra);
      const uint4 hbv = GATH(rb);
      DOTS(ra, ha) DOTS(rb, hbv)
      p += 8;
    }
    if (i < nfull) {
      const uint2 ra = records[p];
      const uint4 ha = GATH(ra);
      DOTS(ra, ha)
      p += 4;
    }
    if (p < end) {
      const uint2 ra = records[p];
      const uint4 ha = GATH(ra);
      DOTS(ra, ha)
    }

    // Merge the 4 quarter-partials (lanes L, L^16, L^32, L^48 share dims).
#define QRED(v)                  \
    v += __shfl_xor(v, 16);      \
    v += __shfl_xor(v, 32);
    QRED(sr0) QRED(sr1) QRED(sr2) QRED(sr3)
    QRED(si0) QRED(si1) QRED(si2) QRED(si3)
#undef QRED

    const float dn = dvec[n];
    if (lane < 16) {
      const int zl = wave * 2 + j;
      uint2 rv, iv;
      rv.x = pack_bf16x2(dn * sr0, dn * sr1);
      rv.y = pack_bf16x2(dn * sr2, dn * sr3);
      iv.x = pack_bf16x2(dn * si0, dn * si1);
      iv.y = pack_bf16x2(dn * si2, dn * si3);
      *reinterpret_cast<uint2*>(&zs[zl][4 * lane]) = rv;
      *reinterpret_cast<uint2*>(&zs[zl][64 + 4 * lane]) = iv;
    }
  }
#undef DOTS
#undef GATH
#undef DOT2
  __syncthreads();

  // Epilogue: Out[node][f] = sum_k Zcat[node][k]*A_comb[k][f] + cvec[f].
  // Wave t computes feature tile [t*16, t*16+16) for all 16 nodes (r1/r8-
  // verified mapping), staging into outbuf for coalesced row writes.
  {
    const int t = wave;
    const int m = lane & 15;
    const int q = lane >> 4;

    bf16x8 a[4];
#pragma unroll
    for (int c = 0; c < 4; ++c)
      a[c] = *reinterpret_cast<const bf16x8*>(&zs[m][c * 32 + q * 8]);

    f32x4 acc = (f32x4){0.f, 0.f, 0.f, 0.f};
    const unsigned short* brow = At + (size_t)(t * 16 + m) * 128 + q * 8;
#pragma unroll
    for (int c = 0; c < 4; ++c) {
      bf16x8 bfrag = *reinterpret_cast<const bf16x8*>(brow + c * 32);
      acc = __builtin_amdgcn_mfma_f32_16x16x32_bf16(a[c], bfrag, acc, 0, 0, 0);
    }

    const int nf = t * 16 + m;
    const float bias = cvec[nf];
#pragma unroll
    for (int r = 0; r < 4; ++r) outbuf[q * 4 + r][nf] = acc[r] + bias;
  }
  __syncthreads();

  // Coalesced store: 512 threads x float4 = 16 nodes x (64 zr + 64 zi).
  {
    const int nl = tid >> 5;    // node 0..15
    const int c = tid & 31;     // chunk: 0..15 -> zr, 16..31 -> zi
    const float4 v = *reinterpret_cast<const float4*>(
        &outbuf[nl][(c & 15) * 4 + (c >> 4) * 64]);
    float* outp = (c < 16) ? zr_out : zi_out;
    *reinterpret_cast<float4*>(
        &outp[(size_t)(node0 + nl) * 64 + (c & 15) * 4]) = v;
  }
}

extern "C" void kernel_launch(void* const* d_in, const int* in_sizes, int n_in,
                              void* d_out, int out_size, void* d_ws, size_t ws_size,
                              hipStream_t stream) {
  const float* h_real = (const float*)d_in[0];
  const float* h_imag = (const float*)d_in[1];
  const float* dvec   = (const float*)d_in[2];
  const float* w_real = (const float*)d_in[3];
  const float* w_imag = (const float*)d_in[4];
  const int*   src    = (const int*)d_in[5];
  const int*   dst    = (const int*)d_in[6];
  const float* W1     = (const float*)d_in[7];
  const float* b1     = (const float*)d_in[8];
  const float* W2     = (const float*)d_in[9];
  const float* b2     = (const float*)d_in[10];

  char* ws = (char*)d_ws;
  unsigned short* At = (unsigned short*)ws;                          // 32 KB
  float* cvec = (float*)(ws + 128 * 128 * 2);                        // 1 KB
  unsigned long long* records = (unsigned long long*)(ws + 33792);   // 12.8 MB
  unsigned* hpack = (unsigned*)(ws + 33792 + (size_t)N_EDGES * 8);   // 25.6 MB
  int* counts = (int*)(ws + 33792 + (size_t)N_EDGES * 8 + (size_t)N_NODES * DIM * 4);
  int* bsum = counts + NCOUNTS;
  int* bpre = bsum + NSB;
  int* inc  = bpre + NSB;

  float* zr_out = (float*)d_out;
  float* zi_out = zr_out + (size_t)N_NODES * DIM;

  setup_fused_kernel<<<PACKB4 + 64 + B1, 256, 0, stream>>>(
      h_real, h_imag, (unsigned*)hpack, W1, b1, W2, b2, At, cvec, dst, counts);
  scan1_kernel<<<NSB, SCAN_BLOCK, 0, stream>>>(counts, bsum);
  scan2_kernel<<<1, 256, 0, stream>>>(bsum, bpre);
  partition_kernel<<<B1, 512, 0, stream>>>(src, dst, dvec, w_real, w_imag,
                                           counts, bpre, records);
  place_kernel<<<K1, 256, 0, stream>>>(records, counts, bpre, inc);
  pull_fused_kernel<<<PULLB, 512, 0, stream>>>(
      (const uint2*)records, inc, dvec, hpack, At, cvec, zr_out, zi_out);
}